// Round 2
// baseline (10657.316 us; speedup 1.0000x reference)
//
#include <hip/hip_runtime.h>
#include <hip/hip_bf16.h>

typedef unsigned short u16;
typedef unsigned int   u32;
typedef __attribute__((ext_vector_type(8))) short s8v;            // MFMA bf16 frag (4 VGPRs)
typedef __attribute__((ext_vector_type(8))) unsigned short u8v;
typedef __attribute__((ext_vector_type(4))) float f32x4;

__device__ __forceinline__ float bf2f(u16 v) {
    union { u32 u; float f; } x; x.u = ((u32)v) << 16; return x.f;
}
__device__ __forceinline__ u16 f2bf(float f) {
    union { float f; u32 u; } x; x.f = f;
    return (u16)((x.u + 0x7fffu + ((x.u >> 16) & 1u)) >> 16);
}

constexpr int Bb = 256, Tt = 32, Ss = 2048, Aa = 64, Pp = 128, SAPd = 2240;

// Decide input dtype from state's bit patterns. bf16 pair: low 16 bits are a bf16
// whose exponent field ((w>>7)&0xFF) sits in ~[118,129] for N(0,1). fp32: low 16
// bits are uniform mantissa bits -> ~10% in range. 64 samples, majority vote.
__global__ void detect_k(const u32* __restrict__ st, int* __restrict__ flag) {
    u32 w = st[threadIdx.x];
    int e = (w >> 7) & 0xFF;
    unsigned long long m = __ballot(e >= 100 && e <= 140);
    if (threadIdx.x == 0) flag[0] = (__popcll(m) >= 32) ? 1 : 0;   // 1 = bf16 inputs
}

// hs0 = [state, act_0, latent] as internal bf16
__global__ __launch_bounds__(256)
void prep_k(const void* __restrict__ state, const void* __restrict__ act,
            const void* __restrict__ latent, u16* __restrict__ hs,
            const int* __restrict__ flagp)
{
    const bool bf = (flagp[0] == 1);
    int i = blockIdx.x * 256 + threadIdx.x;          // grid covers Bb*SAPd exactly
    int b = i / SAPd, k = i - b * SAPd;
    const void* p; size_t src;
    if (k < Ss)            { p = state;  src = (size_t)b * Ss + k; }
    else if (k < Ss + Aa)  { p = act;    src = (size_t)b * (Tt * Aa) + (k - Ss); }
    else                   { p = latent; src = (size_t)b * Pp + (k - Ss - Aa); }
    hs[i] = bf ? ((const u16*)p)[src] : f2bf(((const float*)p)[src]);
}

// C[256 x N] = relu(A[256 x K] @ W[N x K]^T (+bias)), A internal bf16; W is an
// external input (dtype per flag). BM=64 BN=32 BK=64, 2 waves, 16x16x32 MFMA.
// FOLD: W'[n][k] = W[n][k] + W[n][K+k] (row stride 2K) for the cat[h,h] trick.
template<int K, bool BIAS, bool WC, bool FOLD, bool ACT>
__global__ __launch_bounds__(128)
void gemm_k(const u16* __restrict__ Ap, const void* __restrict__ Wp,
            const void* __restrict__ biasp, u16* __restrict__ outp,
            float* __restrict__ cellp, int Nn,
            u16* __restrict__ hsp, const void* __restrict__ actp, int t,
            const int* __restrict__ flagp)
{
    __shared__ __align__(16) u16 As[64][72];
    __shared__ __align__(16) u16 Bs[32][72];
    const bool bf  = (flagp[0] == 1);
    const int tid  = threadIdx.x;
    const int r0   = blockIdx.y * 64;
    const int c0   = blockIdx.x * 32;
    const int lane = tid & 63;
    const int w    = tid >> 6;
    const int m16  = lane & 15;
    const int q    = lane >> 4;

    f32x4 acc[2][2] = {};

    for (int kb = 0; kb < K; kb += 64) {
        __syncthreads();
        #pragma unroll
        for (int i = 0; i < 4; i++) {                 // A tile 64x64 (always bf16)
            int u = tid + i * 128;
            int row = u >> 3, seg = u & 7;
            *(u8v*)&As[row][seg * 8] =
                *(const u8v*)(Ap + (size_t)(r0 + row) * K + kb + seg * 8);
        }
        #pragma unroll
        for (int i = 0; i < 2; i++) {                 // B tile 32x64 (dtype-branched)
            int u = tid + i * 128;
            int row = u >> 3, seg = u & 7;
            int kk = kb + seg * 8;
            u8v v;
            if (FOLD) {
                if (bf) {
                    const u16* p = (const u16*)Wp + (size_t)(c0 + row) * (2 * K) + kk;
                    u8v a = *(const u8v*)p, b2 = *(const u8v*)(p + K);
                    #pragma unroll
                    for (int j = 0; j < 8; j++) v[j] = f2bf(bf2f(a[j]) + bf2f(b2[j]));
                } else {
                    const float* p = (const float*)Wp + (size_t)(c0 + row) * (2 * K) + kk;
                    #pragma unroll
                    for (int j = 0; j < 8; j++) v[j] = f2bf(p[j] + p[K + j]);
                }
            } else {
                if (bf) {
                    v = *(const u8v*)((const u16*)Wp + (size_t)(c0 + row) * K + kk);
                } else {
                    const float* p = (const float*)Wp + (size_t)(c0 + row) * K + kk;
                    #pragma unroll
                    for (int j = 0; j < 8; j++) v[j] = f2bf(p[j]);
                }
            }
            *(u8v*)&Bs[row][seg * 8] = v;
        }
        __syncthreads();
        #pragma unroll
        for (int ks = 0; ks < 2; ks++) {
            s8v a0 = *(const s8v*)&As[w * 32 +      m16][ks * 32 + q * 8];
            s8v a1 = *(const s8v*)&As[w * 32 + 16 + m16][ks * 32 + q * 8];
            s8v b0 = *(const s8v*)&Bs[       m16][ks * 32 + q * 8];
            s8v b1 = *(const s8v*)&Bs[16   + m16][ks * 32 + q * 8];
            acc[0][0] = __builtin_amdgcn_mfma_f32_16x16x32_bf16(a0, b0, acc[0][0], 0, 0, 0);
            acc[0][1] = __builtin_amdgcn_mfma_f32_16x16x32_bf16(a0, b1, acc[0][1], 0, 0, 0);
            acc[1][0] = __builtin_amdgcn_mfma_f32_16x16x32_bf16(a1, b0, acc[1][0], 0, 0, 0);
            acc[1][1] = __builtin_amdgcn_mfma_f32_16x16x32_bf16(a1, b1, acc[1][1], 0, 0, 0);
        }
    }

    float bv[2];
    if (BIAS) {
        #pragma unroll
        for (int ni = 0; ni < 2; ni++) {
            int col = c0 + ni * 16 + m16;
            bv[ni] = bf ? bf2f(((const u16*)biasp)[col]) : ((const float*)biasp)[col];
        }
    }
    #pragma unroll
    for (int mi = 0; mi < 2; mi++) {
        #pragma unroll
        for (int ni = 0; ni < 2; ni++) {
            int col = c0 + ni * 16 + m16;
            #pragma unroll
            for (int r = 0; r < 4; r++) {
                int row = r0 + w * 32 + mi * 16 + q * 4 + r;
                float v = acc[mi][ni][r];
                if (BIAS) v += bv[ni];
                v = fmaxf(v, 0.0f);
                outp[(size_t)row * Nn + col] = f2bf(v);
                if (WC) cellp[(size_t)row * Nn + col] = v;     // fp32 cell init
            }
        }
    }
    if (ACT) {   // refresh act_t slice of hs before K4 reads it (block (0,0) only)
        if (blockIdx.x == 0 && blockIdx.y == 0) {
            for (int i = tid; i < Bb * Aa; i += 128) {
                int b = i >> 6, a = i & 63;
                size_t src = ((size_t)b * Tt + t) * Aa + a;
                u16 v = bf ? ((const u16*)actp)[src] : f2bf(((const float*)actp)[src]);
                hsp[(size_t)b * SAPd + Ss + a] = v;
            }
        }
    }
}

// LSTM gates + cell/hidden update + reward; one block per batch row.
__global__ __launch_bounds__(256)
void gates_k(const u16* __restrict__ cc, float* __restrict__ cbuf,
             u16* __restrict__ hs, void* __restrict__ dout,
             const void* __restrict__ rwW, const void* __restrict__ rwb, int t,
             const int* __restrict__ flagp)
{
    const bool bfio = (flagp[0] == 1);
    const int row = blockIdx.x;
    const int tid = threadIdx.x;
    const int c8  = tid * 8;
    const u16* ccr = cc + (size_t)row * 8192;

    u8v vi = *(const u8v*)&ccr[       c8];
    u8v vf = *(const u8v*)&ccr[2048 + c8];
    u8v vo = *(const u8v*)&ccr[4096 + c8];
    u8v vg = *(const u8v*)&ccr[6144 + c8];
    float cold[8], cnew[8], hnf[8];
    *(float4*)&cold[0] = *(const float4*)&cbuf[(size_t)row * 2048 + c8 + 0];
    *(float4*)&cold[4] = *(const float4*)&cbuf[(size_t)row * 2048 + c8 + 4];
    float rw[8];
    if (bfio) {
        u8v r8 = *(const u8v*)((const u16*)rwW + c8);
        #pragma unroll
        for (int j = 0; j < 8; j++) rw[j] = bf2f(r8[j]);
    } else {
        const float* p = (const float*)rwW + c8;
        #pragma unroll
        for (int j = 0; j < 8; j++) rw[j] = p[j];
    }

    float rsum = 0.0f;
    u8v hv;
    #pragma unroll
    for (int j = 0; j < 8; j++) {
        float ig = 1.0f / (1.0f + __expf(-bf2f(vi[j])));
        float fg = 1.0f / (1.0f + __expf(-bf2f(vf[j])));
        float og = 1.0f / (1.0f + __expf(-bf2f(vo[j])));
        float tg = 1.0f - 2.0f / (__expf(2.0f * bf2f(vg[j])) + 1.0f);   // tanh
        float cn = fg * cold[j] + ig * tg;
        float tc = 1.0f - 2.0f / (__expf(2.0f * cn) + 1.0f);            // tanh
        float hn = og * tc;
        cnew[j] = cn; hnf[j] = hn; hv[j] = f2bf(hn);
        rsum += hn * rw[j];
    }
    *(float4*)&cbuf[(size_t)row * 2048 + c8 + 0] = *(float4*)&cnew[0];
    *(float4*)&cbuf[(size_t)row * 2048 + c8 + 4] = *(float4*)&cnew[4];
    *(u8v*)&hs[(size_t)row * SAPd + c8] = hv;                  // h' for next fc

    size_t pbase = ((size_t)t * 256 + row) * 2048 + c8;
    if (bfio) {
        *(u8v*)&((u16*)dout)[pbase] = hv;
    } else {
        float* fo = (float*)dout;
        *(float4*)&fo[pbase + 0] = *(float4*)&hnf[0];
        *(float4*)&fo[pbase + 4] = *(float4*)&hnf[4];
    }

    #pragma unroll
    for (int off = 32; off > 0; off >>= 1) rsum += __shfl_down(rsum, off);
    __shared__ float red[4];
    if ((tid & 63) == 0) red[tid >> 6] = rsum;
    __syncthreads();
    if (tid == 0) {
        float rb = bfio ? bf2f(((const u16*)rwb)[0]) : ((const float*)rwb)[0];
        float s = red[0] + red[1] + red[2] + red[3] + rb;
        size_t ri = (size_t)8192 * 2048 + (size_t)t * 256 + row;
        if (bfio) ((u16*)dout)[ri] = f2bf(s);
        else      ((float*)dout)[ri] = s;
    }
}

extern "C" void kernel_launch(void* const* d_in, const int* in_sizes, int n_in,
                              void* d_out, int out_size, void* d_ws, size_t ws_size,
                              hipStream_t stream)
{
    const void* state  = d_in[0];
    const void* act    = d_in[1];
    const void* latent = d_in[2];
    const void* fcW    = d_in[3];
    const void* fcb    = d_in[4];
    const void* fc1W   = d_in[5];
    const void* fc2W   = d_in[6];
    const void* WW     = d_in[7];
    const void* rwW    = d_in[8];
    const void* rwb    = d_in[9];
    char* ws = (char*)d_ws;

    // ws layout — 10.6 MB total
    int*   flag = (int*)  (ws + 0);
    u16*   hs   = (u16*)  (ws + 1024);       // [256][2240] bf16
    u16*   h    = (u16*)  (ws + 1147904);    // [256][2048] bf16
    u16*   x1   = (u16*)  (ws + 2196480);    // [256][2048] bf16
    u16*   x2   = (u16*)  (ws + 3245056);    // [256][2048] bf16
    u16*   cc   = (u16*)  (ws + 4293632);    // [256][8192] bf16
    float* cbuf = (float*)(ws + 8487936);    // [256][2048] fp32 cell

    detect_k<<<dim3(1), dim3(64), 0, stream>>>((const u32*)state, flag);
    prep_k<<<dim3(2240), dim3(256), 0, stream>>>(state, act, latent, hs, flag);

    // hidden = cell = relu(fc(hs0))
    gemm_k<2240, true, true, false, false><<<dim3(64, 4), dim3(128), 0, stream>>>(
        hs, fcW, fcb, h, cbuf, 2048, nullptr, nullptr, 0, flag);

    for (int t = 0; t < 32; t++) {
        // x1 = relu(h @ (fc1a+fc1b)^T); also copy act_t into hs
        gemm_k<2048, false, false, true, true><<<dim3(64, 4), dim3(128), 0, stream>>>(
            h, fc1W, nullptr, x1, nullptr, 2048, hs, act, t, flag);
        // x2 = relu(x1 @ fc2^T)
        gemm_k<2048, false, false, false, false><<<dim3(64, 4), dim3(128), 0, stream>>>(
            x1, fc2W, nullptr, x2, nullptr, 2048, nullptr, nullptr, 0, flag);
        // cc = relu(x2 @ W_W^T)
        gemm_k<2048, false, false, false, false><<<dim3(256, 4), dim3(128), 0, stream>>>(
            x2, WW, nullptr, cc, nullptr, 8192, nullptr, nullptr, 0, flag);
        // gates -> c', h' (hs + preds), reward
        gates_k<<<dim3(256), dim3(256), 0, stream>>>(cc, cbuf, hs, d_out, rwW, rwb, t, flag);
        // h = relu(hs @ fc_W^T + b)  (carry discarded at t=31)
        if (t < 31) {
            gemm_k<2240, true, false, false, false><<<dim3(64, 4), dim3(128), 0, stream>>>(
                hs, fcW, fcb, h, nullptr, 2048, nullptr, nullptr, 0, flag);
        }
    }
}

// Round 3
// 4130.516 us; speedup vs baseline: 2.5801x; 2.5801x over previous
//
#include <hip/hip_runtime.h>
#include <hip/hip_bf16.h>

typedef unsigned short u16;
typedef unsigned int   u32;
typedef __attribute__((ext_vector_type(8))) short s8v;            // MFMA bf16 frag
typedef __attribute__((ext_vector_type(8))) unsigned short u8v;
typedef __attribute__((ext_vector_type(4))) unsigned short u4h;
typedef __attribute__((ext_vector_type(4))) float f32x4;

__device__ __forceinline__ float bf2f(u16 v) {
    union { u32 u; float f; } x; x.u = ((u32)v) << 16; return x.f;
}
__device__ __forceinline__ u16 f2bf(float f) {
    union { float f; u32 u; } x; x.f = f;
    return (u16)((x.u + 0x7fffu + ((x.u >> 16) & 1u)) >> 16);
}
__device__ __forceinline__ float sigf(float x)  { return 1.0f / (1.0f + __expf(-x)); }
__device__ __forceinline__ float tanhf_(float x){ return 1.0f - 2.0f / (__expf(2.0f * x) + 1.0f); }

constexpr int Bb = 256, Tt = 32, Ss = 2048, Aa = 64, Pp = 128, SAPd = 2240;

// 1 = bf16 inputs (confirmed in R1 by passing with bf16 path); detector kept as insurance.
__global__ void detect_k(const u32* __restrict__ st, int* __restrict__ flag) {
    u32 w = st[threadIdx.x];
    int e = (w >> 7) & 0xFF;
    unsigned long long m = __ballot(e >= 100 && e <= 140);
    if (threadIdx.x == 0) flag[0] = (__popcll(m) >= 32) ? 1 : 0;
}

// hs0 build + rewards zero + (big ws) fc1s = fc1_W[:,:S] + fc1_W[:,S:]
__global__ __launch_bounds__(256)
void prep_k(const void* __restrict__ state, const void* __restrict__ act,
            const void* __restrict__ latent, const void* __restrict__ fc1W,
            u16* __restrict__ hs, u16* __restrict__ fc1s, float* __restrict__ rewbuf,
            const int* __restrict__ flagp, int big)
{
    const bool bfe = (flagp[0] == 1);
    int g0 = blockIdx.x * 256 + threadIdx.x;
    int stride = gridDim.x * 256;
    for (int i = g0; i < Bb * SAPd; i += stride) {
        int b = i / SAPd, k = i - b * SAPd;
        const void* p; size_t src;
        if (k < Ss)           { p = state;  src = (size_t)b * Ss + k; }
        else if (k < Ss + Aa) { p = act;    src = (size_t)b * (Tt * Aa) + (k - Ss); }
        else                  { p = latent; src = (size_t)b * Pp + (k - Ss - Aa); }
        hs[i] = bfe ? ((const u16*)p)[src] : f2bf(((const float*)p)[src]);
    }
    for (int i = g0; i < Tt * Bb; i += stride) rewbuf[i] = 0.0f;
    if (big) {
        for (int i = g0; i < Ss * Ss; i += stride) {
            int n = i >> 11, k = i & 2047;
            float s;
            if (bfe) s = bf2f(((const u16*)fc1W)[(size_t)n * 4096 + k])
                       + bf2f(((const u16*)fc1W)[(size_t)n * 4096 + 2048 + k]);
            else     s = ((const float*)fc1W)[(size_t)n * 4096 + k]
                       + ((const float*)fc1W)[(size_t)n * 4096 + 2048 + k];
            fc1s[i] = f2bf(s);
        }
    }
}

// C[256 x 2048] = relu(A @ W^T (+bias)). BM=64 BN=16 BK=64, 256thr=4 waves,
// wave-tile 16x16 (wave w rows w*16..+15). Register-dbuf prefetch: issue loads
// for kb+1 right after the LDS-visible barrier; MFMA phase overlaps latency.
template<int K, bool BIAS, bool WC, bool FOLD, bool ACT, bool WBF>
__global__ __launch_bounds__(256)
void gemm_k(const u16* __restrict__ Ap, const void* __restrict__ Wp,
            const void* __restrict__ biasp, u16* __restrict__ outp,
            float* __restrict__ cellp,
            u16* __restrict__ hsp, const void* __restrict__ actp, int t,
            const int* __restrict__ flagp)
{
    __shared__ __align__(16) u16 As[64][72];
    __shared__ __align__(16) u16 Bs[16][72];
    const bool bfe = (flagp[0] == 1);
    const bool wbf = WBF ? true : bfe;
    const int tid = threadIdx.x;
    const int r0 = blockIdx.y * 64;
    const int c0 = blockIdx.x * 16;
    const int lane = tid & 63, w = tid >> 6, m16 = lane & 15, q = lane >> 4;
    const int arow = tid >> 3, aseg = tid & 7;
    const int brow = (tid & 127) >> 3;
    const bool bld = tid < 128;
    constexpr int NK = K / 64;

    f32x4 acc = {};
    u8v ra0, ra1, rbv0, rbv1;
    float4 rf0, rf1, rf2, rf3;

    auto issue = [&](int kb) {
        const u16* ab = Ap + (size_t)(r0 + arow) * K + kb + aseg * 8;
        ra0 = *(const u8v*)ab;
        ra1 = *(const u8v*)(ab + (size_t)32 * K);
        if (bld) {
            int kk = kb + aseg * 8;
            if (FOLD) {
                if (wbf) {
                    const u16* p = (const u16*)Wp + (size_t)(c0 + brow) * (2 * K) + kk;
                    rbv0 = *(const u8v*)p; rbv1 = *(const u8v*)(p + K);
                } else {
                    const float* p = (const float*)Wp + (size_t)(c0 + brow) * (2 * K) + kk;
                    rf0 = *(const float4*)p;       rf1 = *(const float4*)(p + 4);
                    rf2 = *(const float4*)(p + K); rf3 = *(const float4*)(p + K + 4);
                }
            } else {
                if (wbf) {
                    rbv0 = *(const u8v*)((const u16*)Wp + (size_t)(c0 + brow) * K + kk);
                } else {
                    const float* p = (const float*)Wp + (size_t)(c0 + brow) * K + kk;
                    rf0 = *(const float4*)p; rf1 = *(const float4*)(p + 4);
                }
            }
        }
    };
    auto commit = [&]() {
        *(u8v*)&As[arow][aseg * 8]      = ra0;
        *(u8v*)&As[arow + 32][aseg * 8] = ra1;
        if (bld) {
            u8v v;
            if (FOLD) {
                if (wbf) {
                    #pragma unroll
                    for (int j = 0; j < 8; j++) v[j] = f2bf(bf2f(rbv0[j]) + bf2f(rbv1[j]));
                } else {
                    float a0[4], a1[4], b0[4], b1[4];
                    *(float4*)a0 = rf0; *(float4*)a1 = rf1; *(float4*)b0 = rf2; *(float4*)b1 = rf3;
                    #pragma unroll
                    for (int j = 0; j < 4; j++) { v[j] = f2bf(a0[j] + b0[j]); v[4 + j] = f2bf(a1[j] + b1[j]); }
                }
            } else if (wbf) {
                v = rbv0;
            } else {
                float a0[4], a1[4];
                *(float4*)a0 = rf0; *(float4*)a1 = rf1;
                #pragma unroll
                for (int j = 0; j < 4; j++) { v[j] = f2bf(a0[j]); v[4 + j] = f2bf(a1[j]); }
            }
            *(u8v*)&Bs[brow][aseg * 8] = v;
        }
    };

    issue(0);
    for (int ki = 0; ki < NK; ++ki) {
        __syncthreads();
        commit();
        __syncthreads();
        if (ki + 1 < NK) issue((ki + 1) * 64);
        #pragma unroll
        for (int ks = 0; ks < 2; ks++) {
            s8v a = *(const s8v*)&As[w * 16 + m16][ks * 32 + q * 8];
            s8v b = *(const s8v*)&Bs[m16][ks * 32 + q * 8];
            acc = __builtin_amdgcn_mfma_f32_16x16x32_bf16(a, b, acc, 0, 0, 0);
        }
    }

    const int col = c0 + m16;
    float bv = 0.0f;
    if (BIAS) bv = bfe ? bf2f(((const u16*)biasp)[col]) : ((const float*)biasp)[col];
    #pragma unroll
    for (int r = 0; r < 4; r++) {
        int row = r0 + w * 16 + q * 4 + r;
        float v = fmaxf(acc[r] + bv, 0.0f);
        outp[(size_t)row * 2048 + col] = f2bf(v);
        if (WC) cellp[(size_t)row * 2048 + col] = v;
    }
    if (ACT) {          // refresh act_t slice of hs before K4 reads it
        if (blockIdx.x == 0 && blockIdx.y == 0) {
            for (int i = tid; i < Bb * Aa; i += 256) {
                int b = i >> 6, a2 = i & 63;
                size_t src = ((size_t)b * Tt + t) * Aa + a2;
                hsp[(size_t)b * SAPd + Ss + a2] =
                    bfe ? ((const u16*)actp)[src] : f2bf(((const float*)actp)[src]);
            }
        }
    }
}

// Fused: cc = relu(x2 @ W_W^T) + LSTM gates + cell update + h' (hs & preds) + reward partial.
// Block: BM=64 rows x 16 gate-cols x 4 gates; wave g owns gate g (64x16, 4 MFMA-tiles).
__global__ __launch_bounds__(256)
void wgates_k(const u16* __restrict__ Ap, const void* __restrict__ Wp,
              float* __restrict__ cbuf, u16* __restrict__ hsp,
              void* __restrict__ dout, const void* __restrict__ rwWp,
              float* __restrict__ rewbuf, int t, const int* __restrict__ flagp)
{
    __shared__ __align__(16) char smem[18432];
    u16 (*As)[72] = (u16(*)[72])smem;             // [64][72]
    u16 (*Bs)[72] = (u16(*)[72])(smem + 9216);    // [64][72]
    float* gbuf = (float*)smem;                   // overlay: [64 rows][16 j][4 gates] fp32
    const bool bfe = (flagp[0] == 1);
    const int tid = threadIdx.x;
    const int r0 = blockIdx.y * 64, j0 = blockIdx.x * 16;
    const int lane = tid & 63, g = tid >> 6, m16 = lane & 15, q = lane >> 4;
    const int arow = tid >> 3, aseg = tid & 7;
    constexpr int K = 2048, NK = 32;

    f32x4 acc[4] = {};
    u8v ra0, ra1, rb0, rb1;
    float4 rf0, rf1, rf2, rf3;

    auto issue = [&](int kb) {
        const u16* ab = Ap + (size_t)(r0 + arow) * K + kb + aseg * 8;
        ra0 = *(const u8v*)ab;
        ra1 = *(const u8v*)(ab + (size_t)32 * K);
        int kk = kb + aseg * 8;
        #pragma unroll
        for (int i = 0; i < 2; i++) {
            int lrow = arow + i * 32;                              // 0..63
            size_t grow = (size_t)(lrow >> 4) * 2048 + j0 + (lrow & 15);
            if (bfe) {
                u8v vv = *(const u8v*)((const u16*)Wp + grow * K + kk);
                if (i == 0) rb0 = vv; else rb1 = vv;
            } else {
                const float* p = (const float*)Wp + grow * K + kk;
                if (i == 0) { rf0 = *(const float4*)p; rf1 = *(const float4*)(p + 4); }
                else        { rf2 = *(const float4*)p; rf3 = *(const float4*)(p + 4); }
            }
        }
    };
    auto commit = [&]() {
        *(u8v*)&As[arow][aseg * 8]      = ra0;
        *(u8v*)&As[arow + 32][aseg * 8] = ra1;
        if (bfe) {
            *(u8v*)&Bs[arow][aseg * 8]      = rb0;
            *(u8v*)&Bs[arow + 32][aseg * 8] = rb1;
        } else {
            u8v v0, v1;
            float a0[4], a1[4], a2[4], a3[4];
            *(float4*)a0 = rf0; *(float4*)a1 = rf1; *(float4*)a2 = rf2; *(float4*)a3 = rf3;
            #pragma unroll
            for (int j = 0; j < 4; j++) {
                v0[j] = f2bf(a0[j]); v0[4 + j] = f2bf(a1[j]);
                v1[j] = f2bf(a2[j]); v1[4 + j] = f2bf(a3[j]);
            }
            *(u8v*)&Bs[arow][aseg * 8]      = v0;
            *(u8v*)&Bs[arow + 32][aseg * 8] = v1;
        }
    };

    issue(0);
    for (int ki = 0; ki < NK; ++ki) {
        __syncthreads();
        commit();
        __syncthreads();
        if (ki + 1 < NK) issue((ki + 1) * 64);
        #pragma unroll
        for (int ks = 0; ks < 2; ks++) {
            s8v b = *(const s8v*)&Bs[g * 16 + m16][ks * 32 + q * 8];
            #pragma unroll
            for (int mi = 0; mi < 4; mi++) {
                s8v a = *(const s8v*)&As[mi * 16 + m16][ks * 32 + q * 8];
                acc[mi] = __builtin_amdgcn_mfma_f32_16x16x32_bf16(a, b, acc[mi], 0, 0, 0);
            }
        }
    }

    __syncthreads();                               // all waves done reading As/Bs
    #pragma unroll
    for (int mi = 0; mi < 4; mi++)
        #pragma unroll
        for (int r = 0; r < 4; r++) {
            int row = mi * 16 + q * 4 + r;
            gbuf[(row * 16 + m16) * 4 + g] = fmaxf(acc[mi][r], 0.0f);   // relu(cc)
        }
    __syncthreads();

    const int row = tid >> 2, jj = (tid & 3) * 4;
    const int grow = r0 + row;
    float4 cold = *(const float4*)&cbuf[(size_t)grow * 2048 + j0 + jj];
    float rw4[4];
    #pragma unroll
    for (int u = 0; u < 4; u++)
        rw4[u] = bfe ? bf2f(((const u16*)rwWp)[j0 + jj + u]) : ((const float*)rwWp)[j0 + jj + u];

    float cn[4], hnf[4]; u4h hv;
    float rsum = 0.0f;
    #pragma unroll
    for (int u = 0; u < 4; u++) {
        const float* gq = &gbuf[((row * 16) + jj + u) * 4];
        float ig = sigf(gq[0]), fg = sigf(gq[1]), og = sigf(gq[2]), tg = tanhf_(gq[3]);
        float c_ = fg * cold[u] + ig * tg;
        float hn = og * tanhf_(c_);
        cn[u] = c_; hnf[u] = hn; hv[u] = f2bf(hn);
        rsum += hn * rw4[u];
    }
    *(float4*)&cbuf[(size_t)grow * 2048 + j0 + jj] = *(float4*)cn;
    *(u4h*)&hsp[(size_t)grow * SAPd + j0 + jj] = hv;
    size_t pb = ((size_t)t * 256 + grow) * 2048 + j0 + jj;
    if (bfe) *(u4h*)&((u16*)dout)[pb] = hv;
    else     *(float4*)&((float*)dout)[pb] = *(float4*)hnf;

    rsum += __shfl_xor(rsum, 1);
    rsum += __shfl_xor(rsum, 2);
    if ((tid & 3) == 0) atomicAdd(&rewbuf[t * 256 + grow], rsum);
}

__global__ void rewfin_k(const float* __restrict__ rewbuf, void* __restrict__ dout,
                         const void* __restrict__ rwb, const int* __restrict__ flagp) {
    const bool bfe = (flagp[0] == 1);
    int i = blockIdx.x * 256 + threadIdx.x;        // grid 32 -> 8192
    float rb = bfe ? bf2f(((const u16*)rwb)[0]) : ((const float*)rwb)[0];
    float v = rewbuf[i] + rb;
    size_t o = (size_t)Tt * Bb * Ss + i;           // 16777216
    if (bfe) ((u16*)dout)[o] = f2bf(v);
    else     ((float*)dout)[o] = v;
}

extern "C" void kernel_launch(void* const* d_in, const int* in_sizes, int n_in,
                              void* d_out, int out_size, void* d_ws, size_t ws_size,
                              hipStream_t stream)
{
    const void* state  = d_in[0];
    const void* act    = d_in[1];
    const void* latent = d_in[2];
    const void* fcW    = d_in[3];
    const void* fcb    = d_in[4];
    const void* fc1W   = d_in[5];
    const void* fc2W   = d_in[6];
    const void* WW     = d_in[7];
    const void* rwW    = d_in[8];
    const void* rwb    = d_in[9];
    char* ws = (char*)d_ws;

    // ws layout: small path 6.43 MB; big path (+fc1s) 14.81 MB (gated on ws_size)
    int*   flag   = (int*)  (ws + 0);
    u16*   hs     = (u16*)  (ws + 1024);
    u16*   h      = (u16*)  (ws + 1147904);
    u16*   x1     = (u16*)  (ws + 2196480);
    u16*   x2     = (u16*)  (ws + 3245056);
    float* cbuf   = (float*)(ws + 4293632);
    float* rewbuf = (float*)(ws + 6390784);
    u16*   fc1s   = (u16*)  (ws + 6423552);
    const bool big = ws_size >= 14812160ull;       // launch-invariant -> graph-safe

    detect_k<<<dim3(1), dim3(64), 0, stream>>>((const u32*)state, flag);
    prep_k<<<dim3(4096), dim3(256), 0, stream>>>(state, act, latent, fc1W,
                                                 hs, fc1s, rewbuf, flag, big ? 1 : 0);

    // hidden = cell = relu(fc(hs0))
    gemm_k<2240, true, true, false, false, false><<<dim3(128, 4), dim3(256), 0, stream>>>(
        hs, fcW, fcb, h, cbuf, nullptr, nullptr, 0, flag);

    for (int t = 0; t < 32; t++) {
        // x1 = relu(h @ fc1sum^T); block(0,0) also copies act_t into hs
        if (big)
            gemm_k<2048, false, false, false, true, true><<<dim3(128, 4), dim3(256), 0, stream>>>(
                h, fc1s, nullptr, x1, nullptr, hs, act, t, flag);
        else
            gemm_k<2048, false, false, true, true, false><<<dim3(128, 4), dim3(256), 0, stream>>>(
                h, fc1W, nullptr, x1, nullptr, hs, act, t, flag);
        // x2 = relu(x1 @ fc2^T)
        gemm_k<2048, false, false, false, false, false><<<dim3(128, 4), dim3(256), 0, stream>>>(
            x1, fc2W, nullptr, x2, nullptr, nullptr, nullptr, 0, flag);
        // cc = relu(x2 @ W_W^T) fused with gates/cell/h'/preds/reward-partial
        wgates_k<<<dim3(128, 4), dim3(256), 0, stream>>>(
            x2, WW, cbuf, hs, d_out, rwW, rewbuf, t, flag);
        // h = relu(hs @ fc_W^T + b)   (carry discarded at t=31)
        if (t < 31)
            gemm_k<2240, true, false, false, false, false><<<dim3(128, 4), dim3(256), 0, stream>>>(
                hs, fcW, fcb, h, nullptr, nullptr, nullptr, 0, flag);
    }
    rewfin_k<<<dim3(32), dim3(256), 0, stream>>>(rewbuf, d_out, rwb, flag);
}